// Round 1
// baseline (329.361 us; speedup 1.0000x reference)
//
#include <hip/hip_runtime.h>
#include <math.h>

#define IMG_H 1080
#define IMG_W 1920
#define HW (IMG_H * IMG_W)
#define NBATCH 8

// JPEG base quant table (row-major 8x8)
__device__ __constant__ int BASEQ[64] = {
    16, 11, 10, 16, 24, 40, 51, 61,
    12, 12, 14, 19, 26, 58, 60, 55,
    14, 13, 16, 24, 40, 57, 69, 56,
    14, 17, 22, 29, 51, 87, 80, 62,
    18, 22, 37, 56, 68, 109, 103, 77,
    24, 35, 55, 64, 81, 104, 113, 92,
    49, 64, 78, 87, 103, 121, 120, 101,
    72, 92, 95, 98, 112, 100, 103, 99};

__device__ __forceinline__ float clamp255(float v) {
    return fminf(fmaxf(v, 0.0f), 255.0f);
}

// One workgroup = 8 rows x 128 cols strip = 16 DCT blocks. 128 threads.
__global__ __launch_bounds__(128) void h264_kernel(const float* __restrict__ x,
                                                   float* __restrict__ out) {
    __shared__ __align__(16) float yt[8 * 128];   // luma tile, later yd tile
    __shared__ float t2[16 * 72];                 // transpose buffer, 9-padded
    __shared__ float bl[64];                      // DCT basis
    __shared__ float ql[64];                      // quant matrix (QF=28 -> *2.88)

    const int t = threadIdx.x;
    const int w0 = blockIdx.x * 128;
    const int h0 = blockIdx.y * 8;
    const int bat = blockIdx.z;

    // ---- one-time tables (replicate numpy float32 op order exactly) ----
    if (t < 64) {
        int k = t >> 3, n = t & 7;
        float v;
        if (k == 0) {
            v = 0.35355339059327373f;  // np.sqrt(1/8) in f64, cast f32
        } else {
            float a = 3.14159265358979323846f * (float)k;  // pi rounded to f32
            a = a * (2.0f * (float)n + 1.0f);
            a = a / 16.0f;
            v = 0.5f * cosf(a);  // sqrt(2/8) == 0.5 exactly
        }
        bl[t] = v;
        // q = max(base * 144 / 50, 1); all entries > 1 so max is a no-op
        ql[t] = __fdiv_rn((float)(BASEQ[t] * 144), 50.0f);
    }

    const float* xb = x + (size_t)bat * 3 * HW;
    float* ob = out + (size_t)bat * 3 * HW;

    // ---- phase 1: coalesced float4 loads, luma -> LDS; keep b/g/r in regs ----
    float4 Bv[2], Gv[2], Rv[2];
    int gaddr[2];
#pragma unroll
    for (int it = 0; it < 2; ++it) {
        int idx = t + 128 * it;       // 0..255 float4 slots
        int row = idx >> 5;           // 8 rows x 32 float4/row
        int c4 = (idx & 31) << 2;     // float offset in strip
        int ga = (h0 + row) * IMG_W + w0 + c4;
        gaddr[it] = ga;
        Bv[it] = *(const float4*)(xb + ga);
        Gv[it] = *(const float4*)(xb + HW + ga);
        Rv[it] = *(const float4*)(xb + 2 * HW + ga);
        float4 y4;
        // y = (0.114*b + 0.587*g) + 0.299*r, no fma contraction (match ref)
        y4.x = __fadd_rn(__fadd_rn(__fmul_rn(0.114f, Bv[it].x), __fmul_rn(0.587f, Gv[it].x)), __fmul_rn(0.299f, Rv[it].x));
        y4.y = __fadd_rn(__fadd_rn(__fmul_rn(0.114f, Bv[it].y), __fmul_rn(0.587f, Gv[it].y)), __fmul_rn(0.299f, Rv[it].y));
        y4.z = __fadd_rn(__fadd_rn(__fmul_rn(0.114f, Bv[it].z), __fmul_rn(0.587f, Gv[it].z)), __fmul_rn(0.299f, Rv[it].z));
        y4.w = __fadd_rn(__fadd_rn(__fmul_rn(0.114f, Bv[it].w), __fmul_rn(0.587f, Gv[it].w)), __fmul_rn(0.299f, Rv[it].w));
        *(float4*)(yt + row * 128 + c4) = y4;
    }
    __syncthreads();

    // ---- phase 2: column DCT. thread t owns tile-column t (block t/8, col t%8) ----
    const int blk = t >> 3;
    const int l = t & 7;
    float* t2b = t2 + blk * 72;

    float ycol[8];
#pragma unroll
    for (int i = 0; i < 8; ++i) ycol[i] = yt[i * 128 + t];

    float c1[8];
#pragma unroll
    for (int k = 0; k < 8; ++k) {
        float acc = 0.0f;
#pragma unroll
        for (int i = 0; i < 8; ++i) acc = fmaf(bl[k * 8 + i], ycol[i], acc);
        c1[k] = acc;
    }
#pragma unroll
    for (int k = 0; k < 8; ++k) t2b[l * 9 + k] = c1[k];
    __syncthreads();

    // ---- phase 3: row DCT + quantize. coef[k][l] = sum_j t1[k][j]*basis[l][j] ----
    float coef[8];
#pragma unroll
    for (int k = 0; k < 8; ++k) {
        float acc = 0.0f;
#pragma unroll
        for (int j = 0; j < 8; ++j) acc = fmaf(t2b[j * 9 + k], bl[l * 8 + j], acc);
        float q = ql[k * 8 + l];
        // round-half-even division, matches jnp.round(coef/(q+1e-8)) (+1e-8 vanishes in f32)
        coef[k] = __fmul_rn(rintf(__fdiv_rn(acc, q)), q);
    }
    __syncthreads();
#pragma unroll
    for (int k = 0; k < 8; ++k) t2b[l * 9 + k] = coef[k];
    __syncthreads();

    // ---- phase 4: inverse DCT. rec[k][l] = sum_i basis[i][k] * (sum_j C[i][j]*basis[j][l]) ----
    float s[8];
#pragma unroll
    for (int i = 0; i < 8; ++i) {
        float acc = 0.0f;
#pragma unroll
        for (int j = 0; j < 8; ++j) acc = fmaf(t2b[j * 9 + i], bl[j * 8 + l], acc);
        s[i] = acc;
    }
    float yd[8];
#pragma unroll
    for (int k = 0; k < 8; ++k) {
        float acc = 0.0f;
#pragma unroll
        for (int i = 0; i < 8; ++i) acc = fmaf(bl[i * 8 + k], s[i], acc);
        yd[k] = __fsub_rn(acc, ycol[k]);
    }
    // write yd back into yt (each thread owns its own column -> no race)
#pragma unroll
    for (int k = 0; k < 8; ++k) yt[k * 128 + t] = yd[k];
    __syncthreads();

    // ---- phase 5: vectorized epilogue reusing registered b/g/r ----
#pragma unroll
    for (int it = 0; it < 2; ++it) {
        int idx = t + 128 * it;
        int row = idx >> 5;
        int c4 = (idx & 31) << 2;
        float4 y4 = *(float4*)(yt + row * 128 + c4);
        int ga = gaddr[it];
        float4 o0, o1, o2;
        o0.x = clamp255(__fadd_rn(Bv[it].x, __fmul_rn(0.114f, y4.x)));
        o0.y = clamp255(__fadd_rn(Bv[it].y, __fmul_rn(0.114f, y4.y)));
        o0.z = clamp255(__fadd_rn(Bv[it].z, __fmul_rn(0.114f, y4.z)));
        o0.w = clamp255(__fadd_rn(Bv[it].w, __fmul_rn(0.114f, y4.w)));
        o1.x = clamp255(__fadd_rn(Gv[it].x, __fmul_rn(0.587f, y4.x)));
        o1.y = clamp255(__fadd_rn(Gv[it].y, __fmul_rn(0.587f, y4.y)));
        o1.z = clamp255(__fadd_rn(Gv[it].z, __fmul_rn(0.587f, y4.z)));
        o1.w = clamp255(__fadd_rn(Gv[it].w, __fmul_rn(0.587f, y4.w)));
        o2.x = clamp255(__fadd_rn(Rv[it].x, __fmul_rn(0.299f, y4.x)));
        o2.y = clamp255(__fadd_rn(Rv[it].y, __fmul_rn(0.299f, y4.y)));
        o2.z = clamp255(__fadd_rn(Rv[it].z, __fmul_rn(0.299f, y4.z)));
        o2.w = clamp255(__fadd_rn(Rv[it].w, __fmul_rn(0.299f, y4.w)));
        *(float4*)(ob + ga) = o0;
        *(float4*)(ob + HW + ga) = o1;
        *(float4*)(ob + 2 * HW + ga) = o2;
    }
}

extern "C" void kernel_launch(void* const* d_in, const int* in_sizes, int n_in,
                              void* d_out, int out_size, void* d_ws, size_t ws_size,
                              hipStream_t stream) {
    const float* x = (const float*)d_in[0];
    float* out = (float*)d_out;
    dim3 grid(IMG_W / 128, IMG_H / 8, NBATCH);  // 15 x 135 x 8
    dim3 block(128);
    h264_kernel<<<grid, block, 0, stream>>>(x, out);
}

// Round 2
// 315.979 us; speedup vs baseline: 1.0424x; 1.0424x over previous
//
#include <hip/hip_runtime.h>
#include <math.h>

#define IMG_H 1080
#define IMG_W 1920
#define HW (IMG_H * IMG_W)
#define NBATCH 8

typedef float f4 __attribute__((ext_vector_type(4)));

// JPEG base quant table (row-major 8x8)
__device__ __constant__ int BASEQ[64] = {
    16, 11, 10, 16, 24, 40, 51, 61,
    12, 12, 14, 19, 26, 58, 60, 55,
    14, 13, 16, 24, 40, 57, 69, 56,
    14, 17, 22, 29, 51, 87, 80, 62,
    18, 22, 37, 56, 68, 109, 103, 77,
    24, 35, 55, 64, 81, 104, 113, 92,
    49, 64, 78, 87, 103, 121, 120, 101,
    72, 92, 95, 98, 112, 100, 103, 99};

__device__ __forceinline__ float clamp255(float v) {
    return fminf(fmaxf(v, 0.0f), 255.0f);
}

// Wave-internal LDS hand-off: order compiler, wait LDS writes retired
// (lgkmcnt(0) only — vmcnt left unconstrained so B/G/R loads stay in flight).
__device__ __forceinline__ void wave_lds_fence() {
    __builtin_amdgcn_wave_barrier();
    __builtin_amdgcn_s_waitcnt(0xC07F);  // vmcnt(63) expcnt(7) lgkmcnt(0)
    __builtin_amdgcn_wave_barrier();
}

// 192 threads = 3 independent waves; each wave owns an 8-row x 64-col strip
// (8 DCT blocks). No s_barrier anywhere: all LDS traffic is wave-private.
__global__ __launch_bounds__(192) void h264_kernel(const float* __restrict__ x,
                                                   float* __restrict__ out) {
    __shared__ __align__(16) float yt[3 * 512];  // per-wave luma/yd tile (8x64)
    __shared__ float t2[3 * 576];                // per-wave transpose buf (8 blk x 72, 9-padded)
    __shared__ float bl[64];                     // DCT basis (dup-written by every wave)
    __shared__ float ql[64];                     // quant matrix (QF=28 -> *2.88)

    const int t = threadIdx.x;
    const int wave = t >> 6;
    const int lane = t & 63;

    // ---- tables: each wave writes the full 64 entries (identical values,
    //      benign cross-wave duplicate write; wave reads only after its own write)
    {
        int k = lane >> 3, n = lane & 7;
        float v;
        if (k == 0) {
            v = 0.35355339059327373f;  // np.sqrt(1/8) in f64, cast f32
        } else {
            float a = 3.14159265358979323846f * (float)k;  // pi rounded to f32
            a = a * (2.0f * (float)n + 1.0f);
            a = a / 16.0f;
            v = 0.5f * cosf(a);  // sqrt(2/8) == 0.5 exactly
        }
        bl[lane] = v;
        // q = max(base * 144 / 50, 1); all entries > 1 so max is a no-op
        ql[lane] = __fdiv_rn((float)(BASEQ[lane] * 144), 50.0f);
    }

    const int h0 = blockIdx.y * 8;
    const int wcol0 = blockIdx.x * 192 + wave * 64;
    const int bat = blockIdx.z;
    const float* xb = x + (size_t)bat * 3 * HW;
    float* ob = out + (size_t)bat * 3 * HW;

    float* ytw = yt + wave * 512;
    float* t2w = t2 + wave * 576;

    // ---- phase 1: nontemporal f4 loads, luma -> wave-private LDS;
    //      keep b/g/r in registers for the epilogue
    f4 Bv[2], Gv[2], Rv[2];
    int gaddr[2];
#pragma unroll
    for (int it = 0; it < 2; ++it) {
        int idx = lane + (it << 6);   // 0..127 f4 slots of this wave's strip
        int row = idx >> 4;           // 8 rows x 16 f4/row
        int c4 = (idx & 15) << 2;     // float offset within strip
        int ga = (h0 + row) * IMG_W + wcol0 + c4;
        gaddr[it] = ga;
        Bv[it] = __builtin_nontemporal_load((const f4*)(xb + ga));
        Gv[it] = __builtin_nontemporal_load((const f4*)(xb + HW + ga));
        Rv[it] = __builtin_nontemporal_load((const f4*)(xb + 2 * HW + ga));
        f4 y4;
        // y = (0.114*b + 0.587*g) + 0.299*r, no fma contraction (match ref)
        y4.x = __fadd_rn(__fadd_rn(__fmul_rn(0.114f, Bv[it].x), __fmul_rn(0.587f, Gv[it].x)), __fmul_rn(0.299f, Rv[it].x));
        y4.y = __fadd_rn(__fadd_rn(__fmul_rn(0.114f, Bv[it].y), __fmul_rn(0.587f, Gv[it].y)), __fmul_rn(0.299f, Rv[it].y));
        y4.z = __fadd_rn(__fadd_rn(__fmul_rn(0.114f, Bv[it].z), __fmul_rn(0.587f, Gv[it].z)), __fmul_rn(0.299f, Rv[it].z));
        y4.w = __fadd_rn(__fadd_rn(__fmul_rn(0.114f, Bv[it].w), __fmul_rn(0.587f, Gv[it].w)), __fmul_rn(0.299f, Rv[it].w));
        *(f4*)(ytw + row * 64 + c4) = y4;
    }
    wave_lds_fence();

    // ---- phase 2: column DCT. lane owns strip-column `lane` (blk lane/8, col lane%8)
    const int blk = lane >> 3;
    const int l = lane & 7;
    float* t2b = t2w + blk * 72;

    float ycol[8];
#pragma unroll
    for (int i = 0; i < 8; ++i) ycol[i] = ytw[i * 64 + lane];

    float c1[8];
#pragma unroll
    for (int k = 0; k < 8; ++k) {
        float acc = 0.0f;
#pragma unroll
        for (int i = 0; i < 8; ++i) acc = fmaf(bl[k * 8 + i], ycol[i], acc);
        c1[k] = acc;
    }
#pragma unroll
    for (int k = 0; k < 8; ++k) t2b[l * 9 + k] = c1[k];
    wave_lds_fence();

    // ---- phase 3: row DCT + quantize. coef[k] (column l of C), k=0..7
    float coef[8];
#pragma unroll
    for (int k = 0; k < 8; ++k) {
        float acc = 0.0f;
#pragma unroll
        for (int j = 0; j < 8; ++j) acc = fmaf(t2b[j * 9 + k], bl[l * 8 + j], acc);
        float q = ql[k * 8 + l];
        // round-half-even division, matches jnp.round(coef/(q+1e-8)) (+1e-8 vanishes in f32)
        coef[k] = __fmul_rn(rintf(__fdiv_rn(acc, q)), q);
    }
    wave_lds_fence();  // reads retired before overwrite (WAR)
#pragma unroll
    for (int k = 0; k < 8; ++k) t2b[l * 9 + k] = coef[k];
    wave_lds_fence();

    // ---- phase 4: inverse DCT
    float s[8];
#pragma unroll
    for (int i = 0; i < 8; ++i) {
        float acc = 0.0f;
#pragma unroll
        for (int j = 0; j < 8; ++j) acc = fmaf(t2b[j * 9 + i], bl[j * 8 + l], acc);
        s[i] = acc;
    }
    float yd[8];
#pragma unroll
    for (int k = 0; k < 8; ++k) {
        float acc = 0.0f;
#pragma unroll
        for (int i = 0; i < 8; ++i) acc = fmaf(bl[i * 8 + k], s[i], acc);
        yd[k] = __fsub_rn(acc, ycol[k]);
    }
#pragma unroll
    for (int k = 0; k < 8; ++k) ytw[k * 64 + lane] = yd[k];
    wave_lds_fence();

    // ---- phase 5: vectorized epilogue reusing registered b/g/r; nt stores
#pragma unroll
    for (int it = 0; it < 2; ++it) {
        int idx = lane + (it << 6);
        int row = idx >> 4;
        int c4 = (idx & 15) << 2;
        f4 y4 = *(f4*)(ytw + row * 64 + c4);
        int ga = gaddr[it];
        f4 o0, o1, o2;
        o0.x = clamp255(__fadd_rn(Bv[it].x, __fmul_rn(0.114f, y4.x)));
        o0.y = clamp255(__fadd_rn(Bv[it].y, __fmul_rn(0.114f, y4.y)));
        o0.z = clamp255(__fadd_rn(Bv[it].z, __fmul_rn(0.114f, y4.z)));
        o0.w = clamp255(__fadd_rn(Bv[it].w, __fmul_rn(0.114f, y4.w)));
        o1.x = clamp255(__fadd_rn(Gv[it].x, __fmul_rn(0.587f, y4.x)));
        o1.y = clamp255(__fadd_rn(Gv[it].y, __fmul_rn(0.587f, y4.y)));
        o1.z = clamp255(__fadd_rn(Gv[it].z, __fmul_rn(0.587f, y4.z)));
        o1.w = clamp255(__fadd_rn(Gv[it].w, __fmul_rn(0.587f, y4.w)));
        o2.x = clamp255(__fadd_rn(Rv[it].x, __fmul_rn(0.299f, y4.x)));
        o2.y = clamp255(__fadd_rn(Rv[it].y, __fmul_rn(0.299f, y4.y)));
        o2.z = clamp255(__fadd_rn(Rv[it].z, __fmul_rn(0.299f, y4.z)));
        o2.w = clamp255(__fadd_rn(Rv[it].w, __fmul_rn(0.299f, y4.w)));
        __builtin_nontemporal_store(o0, (f4*)(ob + ga));
        __builtin_nontemporal_store(o1, (f4*)(ob + HW + ga));
        __builtin_nontemporal_store(o2, (f4*)(ob + 2 * HW + ga));
    }
}

extern "C" void kernel_launch(void* const* d_in, const int* in_sizes, int n_in,
                              void* d_out, int out_size, void* d_ws, size_t ws_size,
                              hipStream_t stream) {
    const float* x = (const float*)d_in[0];
    float* out = (float*)d_out;
    dim3 grid(IMG_W / 192, IMG_H / 8, NBATCH);  // 10 x 135 x 8
    dim3 block(192);
    h264_kernel<<<grid, block, 0, stream>>>(x, out);
}